// Round 1
// baseline (598.825 us; speedup 1.0000x reference)
//
#include <hip/hip_runtime.h>

#define N_NODES 100000
#define N_EDGES 1600000

// ---------------------------------------------------------------------------
// K1: degree counting.  dis <- out-degree(src), disg <- in-degree(dst)
// ---------------------------------------------------------------------------
__global__ __launch_bounds__(256) void k_deg(const int* __restrict__ src,
                                             const int* __restrict__ dst,
                                             float* __restrict__ degs,
                                             float* __restrict__ degd) {
    int e = blockIdx.x * 256 + threadIdx.x;
    if (e < N_EDGES) {
        atomicAdd(&degs[src[e]], 1.0f);
        atomicAdd(&degd[dst[e]], 1.0f);
    }
}

// ---------------------------------------------------------------------------
// K2: per-node normalizers.
//   dis[i]  = deg_src>0 ? rsqrt(deg_src) : 0        (ChebConv sym-norm)
//   disg[i] = rsqrt(deg_dst + 1)                    (GCN w/ self-loop)
// ---------------------------------------------------------------------------
__global__ __launch_bounds__(256) void k_norm(float* __restrict__ dis,
                                              float* __restrict__ disg) {
    int i = blockIdx.x * 256 + threadIdx.x;
    if (i < N_NODES) {
        float d = dis[i];
        dis[i]  = d > 0.0f ? rsqrtf(d) : 0.0f;
        disg[i] = rsqrtf(disg[i] + 1.0f);
    }
}

// ---------------------------------------------------------------------------
// K3: Lx[dst] += -(dis[src]*dis[dst]) * x[src]   (32 lanes per edge)
// ---------------------------------------------------------------------------
__global__ __launch_bounds__(256) void k_lx(const int* __restrict__ src,
                                            const int* __restrict__ dst,
                                            const float* __restrict__ dis,
                                            const float* __restrict__ x,
                                            float* __restrict__ Lx) {
    int id = blockIdx.x * 256 + threadIdx.x;     // E*32 = 51.2M < 2^31
    int e = id >> 5, f = id & 31;
    int s = src[e], d = dst[e];
    float w = -(dis[s] * dis[d]);
    atomicAdd(&Lx[d * 32 + f], w * x[s * 32 + f]);
}

// ---------------------------------------------------------------------------
// K4: per-node fused GRU-gate GEMMs + GCN weight GEMM.
//   Z  = sigmoid(x@Wz0 + Lx@Wz1 + bz);  Ht = tanh(x@Wh0 + Lx@Wh1 + bh)
//   H  = (1-Z)*Ht;  hw = H@Wgcn;  h_init = disg^2 * hw   (self-loop term)
// 8 nodes per 256-thread block; lane = output feature; weights in LDS.
// ---------------------------------------------------------------------------
__global__ __launch_bounds__(256) void k_node(
        const float* __restrict__ x, const float* __restrict__ Lx,
        const float* __restrict__ W_xz, const float* __restrict__ b_xz,
        const float* __restrict__ b_hz,
        const float* __restrict__ W_xh, const float* __restrict__ b_xh,
        const float* __restrict__ b_hh,
        const float* __restrict__ W_gcn, const float* __restrict__ disg,
        float* __restrict__ hw, float* __restrict__ hout) {
    __shared__ float sW[5 * 1024];   // Wz0,Wz1,Wh0,Wh1,Wgcn  (k-major: [k][f])
    __shared__ float sbz[32], sbh[32];
    int tid = threadIdx.x;
    for (int i = tid; i < 2048; i += 256) { sW[i] = W_xz[i]; sW[2048 + i] = W_xh[i]; }
    for (int i = tid; i < 1024; i += 256) { sW[4096 + i] = W_gcn[i]; }
    if (tid < 32) { sbz[tid] = b_xz[tid] + b_hz[tid]; sbh[tid] = b_xh[tid] + b_hh[tid]; }
    __syncthreads();

    int node = blockIdx.x * 8 + (tid >> 5);   // N % 8 == 0, no tail
    int lane = tid & 31;
    const float* Wz0 = sW;
    const float* Wz1 = sW + 1024;
    const float* Wh0 = sW + 2048;
    const float* Wh1 = sW + 3072;
    const float* Wg  = sW + 4096;

    float xv = x[node * 32 + lane];
    float lv = Lx[node * 32 + lane];
    float z = sbz[lane], t = sbh[lane];
#pragma unroll
    for (int k = 0; k < 32; ++k) {
        float xk = __shfl(xv, k, 32);
        float lk = __shfl(lv, k, 32);
        z = fmaf(xk, Wz0[k * 32 + lane], z);
        z = fmaf(lk, Wz1[k * 32 + lane], z);
        t = fmaf(xk, Wh0[k * 32 + lane], t);
        t = fmaf(lk, Wh1[k * 32 + lane], t);
    }
    float Z = 1.0f / (1.0f + expf(-z));
    float H = (1.0f - Z) * tanhf(t);

    float hwv = 0.0f;
#pragma unroll
    for (int k = 0; k < 32; ++k) {
        float Hk = __shfl(H, k, 32);
        hwv = fmaf(Hk, Wg[k * 32 + lane], hwv);
    }
    hw[node * 32 + lane] = hwv;
    float dg = disg[node];
    hout[node * 32 + lane] = dg * dg * hwv;   // self-loop seed for GCN agg
}

// ---------------------------------------------------------------------------
// K5: h[dst] += (disg[src]*disg[dst]) * hw[src]   (32 lanes per edge)
// ---------------------------------------------------------------------------
__global__ __launch_bounds__(256) void k_gcn(const int* __restrict__ src,
                                             const int* __restrict__ dst,
                                             const float* __restrict__ disg,
                                             const float* __restrict__ hw,
                                             float* __restrict__ h) {
    int id = blockIdx.x * 256 + threadIdx.x;
    int e = id >> 5, f = id & 31;
    int s = src[e], d = dst[e];
    float gw = disg[s] * disg[d];
    atomicAdd(&h[d * 32 + f], gw * hw[s * 32 + f]);
}

// ---------------------------------------------------------------------------
// K6: out[i] = relu(h[i] + b_gcn) . W_lin + b_lin   (32-lane dot + reduce)
// ---------------------------------------------------------------------------
__global__ __launch_bounds__(256) void k_out(const float* __restrict__ h,
                                             const float* __restrict__ b_gcn,
                                             const float* __restrict__ W_lin,
                                             const float* __restrict__ b_lin,
                                             float* __restrict__ out) {
    int tid = threadIdx.x;
    int node = blockIdx.x * 8 + (tid >> 5);
    int lane = tid & 31;
    float v = fmaxf(h[node * 32 + lane] + b_gcn[lane], 0.0f) * W_lin[lane];
#pragma unroll
    for (int o = 16; o > 0; o >>= 1) v += __shfl_xor(v, o, 32);
    if (lane == 0) out[node] = v + b_lin[0];
}

extern "C" void kernel_launch(void* const* d_in, const int* in_sizes, int n_in,
                              void* d_out, int out_size, void* d_ws, size_t ws_size,
                              hipStream_t stream) {
    const float* x     = (const float*)d_in[0];
    const int*   ei    = (const int*)d_in[1];
    const int*   src   = ei;
    const int*   dst   = ei + N_EDGES;
    const float* W_xz  = (const float*)d_in[2];
    const float* b_xz  = (const float*)d_in[3];
    const float* b_hz  = (const float*)d_in[5];
    // W_xr/b_xr/W_hr/b_hr (d_in[6..9]) are dead: R only multiplies H0 == 0.
    const float* W_xh  = (const float*)d_in[10];
    const float* b_xh  = (const float*)d_in[11];
    const float* b_hh  = (const float*)d_in[13];
    const float* W_gcn = (const float*)d_in[14];
    const float* b_gcn = (const float*)d_in[15];
    const float* W_lin = (const float*)d_in[16];
    const float* b_lin = (const float*)d_in[17];
    float* out = (float*)d_out;

    // Workspace layout (floats): [dis N][disg N][Lx 32N][hw 32N][h 32N] = 98N
    float* ws   = (float*)d_ws;
    float* dis  = ws;
    float* disg = ws + (size_t)N_NODES;
    float* Lx   = ws + (size_t)2 * N_NODES;
    float* hw   = ws + (size_t)34 * N_NODES;
    float* h    = ws + (size_t)66 * N_NODES;

    // Zero dis+disg+Lx in one contiguous memset (13.6 MB).
    hipMemsetAsync(dis, 0, (size_t)34 * N_NODES * sizeof(float), stream);

    k_deg <<<(N_EDGES + 255) / 256, 256, 0, stream>>>(src, dst, dis, disg);
    k_norm<<<(N_NODES + 255) / 256, 256, 0, stream>>>(dis, disg);
    k_lx  <<<(N_EDGES * 32) / 256, 256, 0, stream>>>(src, dst, dis, x, Lx);
    k_node<<<N_NODES / 8, 256, 0, stream>>>(x, Lx, W_xz, b_xz, b_hz,
                                            W_xh, b_xh, b_hh, W_gcn, disg, hw, h);
    k_gcn <<<(N_EDGES * 32) / 256, 256, 0, stream>>>(src, dst, disg, hw, h);
    k_out <<<N_NODES / 8, 256, 0, stream>>>(h, b_gcn, W_lin, b_lin, out);
}

// Round 2
// 469.001 us; speedup vs baseline: 1.2768x; 1.2768x over previous
//
#include <hip/hip_runtime.h>

#define N_NODES 100000
#define N_EDGES 1600000

// ---------------------------------------------------------------------------
// K1: integer degree counts.  cs <- out-degree(src), cd <- in-degree(dst)
// ---------------------------------------------------------------------------
__global__ __launch_bounds__(256) void k_deg(const int* __restrict__ src,
                                             const int* __restrict__ dst,
                                             int* __restrict__ cs,
                                             int* __restrict__ cd) {
    int e = blockIdx.x * 256 + threadIdx.x;
    if (e < N_EDGES) {
        atomicAdd(&cs[src[e]], 1);
        atomicAdd(&cd[dst[e]], 1);
    }
}

// ---------------------------------------------------------------------------
// K2: per-node normalizers + CSR slot allocation.
//   dis  = out_deg>0 ? rsqrt(out_deg) : 0     (ChebConv sym-norm)
//   disg = rsqrt(in_deg + 1)                  (GCN w/ self-loop)
//   start = atomicAdd(gcur, in_deg)           (contiguous slot range per node;
//                                              LLVM wave-aggregates the atomic)
// ---------------------------------------------------------------------------
__global__ __launch_bounds__(256) void k_alloc(const int* __restrict__ cs,
                                               const int* __restrict__ cd,
                                               int* __restrict__ gcur,
                                               int* __restrict__ start,
                                               int* __restrict__ cursor,
                                               float* __restrict__ dis,
                                               float* __restrict__ disg) {
    int i = blockIdx.x * 256 + threadIdx.x;
    if (i < N_NODES) {
        int c = cs[i], d = cd[i];
        dis[i]  = c > 0 ? rsqrtf((float)c) : 0.0f;
        disg[i] = rsqrtf((float)d + 1.0f);
        int st = atomicAdd(gcur, d);
        start[i]  = st;
        cursor[i] = st;
    }
}

// ---------------------------------------------------------------------------
// K3: scatter edges into dst-grouped CSR with precomputed weights.
//   csr_s[pos] = src,  csr_wl[pos] = -(dis[s]*dis[d]),  csr_wg = disg[s]*disg[d]
// ---------------------------------------------------------------------------
__global__ __launch_bounds__(256) void k_scatter(const int* __restrict__ src,
                                                 const int* __restrict__ dst,
                                                 const float* __restrict__ dis,
                                                 const float* __restrict__ disg,
                                                 int* __restrict__ cursor,
                                                 int* __restrict__ csr_s,
                                                 float* __restrict__ csr_wl,
                                                 float* __restrict__ csr_wg) {
    int e = blockIdx.x * 256 + threadIdx.x;
    if (e < N_EDGES) {
        int s = src[e], d = dst[e];
        int pos = atomicAdd(&cursor[d], 1);
        csr_s[pos]  = s;
        csr_wl[pos] = -(dis[s] * dis[d]);
        csr_wg[pos] = disg[s] * disg[d];
    }
}

// ---------------------------------------------------------------------------
// K4: fused Lx-gather + GRU-gate GEMMs + GCN weight GEMM.
//   Lx   = sum_{e->node} wl_e * x[src_e]        (registers, 32 lanes/node)
//   Z    = sigmoid(x@Wz0 + Lx@Wz1 + bz);  Ht = tanh(x@Wh0 + Lx@Wh1 + bh)
//   hw   = ((1-Z)*Ht) @ Wgcn
// 8 nodes per 256-thread block; lane = feature; weights in LDS.
// ---------------------------------------------------------------------------
__global__ __launch_bounds__(256) void k_node(
        const float* __restrict__ x,
        const int* __restrict__ csr_s, const float* __restrict__ csr_wl,
        const int* __restrict__ start, const int* __restrict__ cd,
        const float* __restrict__ W_xz, const float* __restrict__ b_xz,
        const float* __restrict__ b_hz,
        const float* __restrict__ W_xh, const float* __restrict__ b_xh,
        const float* __restrict__ b_hh,
        const float* __restrict__ W_gcn,
        float* __restrict__ hw) {
    __shared__ float sW[5 * 1024];   // Wz0,Wz1,Wh0,Wh1,Wgcn  (k-major: [k][f])
    __shared__ float sbz[32], sbh[32];
    int tid = threadIdx.x;
    for (int i = tid; i < 2048; i += 256) { sW[i] = W_xz[i]; sW[2048 + i] = W_xh[i]; }
    for (int i = tid; i < 1024; i += 256) { sW[4096 + i] = W_gcn[i]; }
    if (tid < 32) { sbz[tid] = b_xz[tid] + b_hz[tid]; sbh[tid] = b_xh[tid] + b_hh[tid]; }
    __syncthreads();

    int node = blockIdx.x * 8 + (tid >> 5);   // N % 8 == 0, no tail
    int lane = tid & 31;
    int st = start[node], cn = cd[node];

    // --- gather Lx into registers (no atomics, no Lx array) ---
    float lv = 0.0f;
    int j = 0;
    for (; j + 2 <= cn; j += 2) {
        int   s0 = csr_s[st + j],      s1 = csr_s[st + j + 1];
        float w0 = csr_wl[st + j],     w1 = csr_wl[st + j + 1];
        float v0 = x[s0 * 32 + lane],  v1 = x[s1 * 32 + lane];
        lv = fmaf(w0, v0, lv);
        lv = fmaf(w1, v1, lv);
    }
    if (j < cn) {
        int s0 = csr_s[st + j];
        lv = fmaf(csr_wl[st + j], x[s0 * 32 + lane], lv);
    }

    const float* Wz0 = sW;
    const float* Wz1 = sW + 1024;
    const float* Wh0 = sW + 2048;
    const float* Wh1 = sW + 3072;
    const float* Wg  = sW + 4096;

    float xv = x[node * 32 + lane];
    float z = sbz[lane], t = sbh[lane];
#pragma unroll
    for (int k = 0; k < 32; ++k) {
        float xk = __shfl(xv, k, 32);
        float lk = __shfl(lv, k, 32);
        z = fmaf(xk, Wz0[k * 32 + lane], z);
        z = fmaf(lk, Wz1[k * 32 + lane], z);
        t = fmaf(xk, Wh0[k * 32 + lane], t);
        t = fmaf(lk, Wh1[k * 32 + lane], t);
    }
    float Z = 1.0f / (1.0f + expf(-z));
    float H = (1.0f - Z) * tanhf(t);

    float hwv = 0.0f;
#pragma unroll
    for (int k = 0; k < 32; ++k) {
        float Hk = __shfl(H, k, 32);
        hwv = fmaf(Hk, Wg[k * 32 + lane], hwv);
    }
    hw[node * 32 + lane] = hwv;
}

// ---------------------------------------------------------------------------
// K5: fused GCN-gather + self-loop + bias + relu + W_lin dot.
//   h = sum_{e->node} wg_e * hw[src_e] + disg^2 * hw[node] + b_gcn
//   out[node] = relu(h) . W_lin + b_lin
// ---------------------------------------------------------------------------
__global__ __launch_bounds__(256) void k_out(
        const float* __restrict__ hw,
        const int* __restrict__ csr_s, const float* __restrict__ csr_wg,
        const int* __restrict__ start, const int* __restrict__ cd,
        const float* __restrict__ disg,
        const float* __restrict__ b_gcn,
        const float* __restrict__ W_lin, const float* __restrict__ b_lin,
        float* __restrict__ out) {
    int tid = threadIdx.x;
    int node = blockIdx.x * 8 + (tid >> 5);
    int lane = tid & 31;
    int st = start[node], cn = cd[node];

    float acc = 0.0f;
    int j = 0;
    for (; j + 2 <= cn; j += 2) {
        int   s0 = csr_s[st + j],      s1 = csr_s[st + j + 1];
        float w0 = csr_wg[st + j],     w1 = csr_wg[st + j + 1];
        float v0 = hw[s0 * 32 + lane], v1 = hw[s1 * 32 + lane];
        acc = fmaf(w0, v0, acc);
        acc = fmaf(w1, v1, acc);
    }
    if (j < cn) {
        int s0 = csr_s[st + j];
        acc = fmaf(csr_wg[st + j], hw[s0 * 32 + lane], acc);
    }

    float dg = disg[node];
    acc = fmaf(dg * dg, hw[node * 32 + lane], acc);   // self loop

    float v = fmaxf(acc + b_gcn[lane], 0.0f) * W_lin[lane];
#pragma unroll
    for (int o = 16; o > 0; o >>= 1) v += __shfl_xor(v, o, 32);
    if (lane == 0) out[node] = v + b_lin[0];
}

extern "C" void kernel_launch(void* const* d_in, const int* in_sizes, int n_in,
                              void* d_out, int out_size, void* d_ws, size_t ws_size,
                              hipStream_t stream) {
    const float* x     = (const float*)d_in[0];
    const int*   ei    = (const int*)d_in[1];
    const int*   src   = ei;
    const int*   dst   = ei + N_EDGES;
    const float* W_xz  = (const float*)d_in[2];
    const float* b_xz  = (const float*)d_in[3];
    const float* b_hz  = (const float*)d_in[5];
    // W_xr/b_xr/W_hr/b_hr (d_in[6..9]) are dead: R only multiplies H0 == 0.
    const float* W_xh  = (const float*)d_in[10];
    const float* b_xh  = (const float*)d_in[11];
    const float* b_hh  = (const float*)d_in[13];
    const float* W_gcn = (const float*)d_in[14];
    const float* b_gcn = (const float*)d_in[15];
    const float* W_lin = (const float*)d_in[16];
    const float* b_lin = (const float*)d_in[17];
    float* out = (float*)d_out;

    // Workspace layout.  Zeroed region first: [cs N][cd N][gcur 4] ints.
    int* wsi     = (int*)d_ws;
    int* cs      = wsi;                                  // N
    int* cd      = cs + N_NODES;                         // N
    int* gcur    = cd + N_NODES;                         // 4 (1 used)
    int* start   = gcur + 4;                             // N
    int* cursor  = start + N_NODES;                      // N
    float* dis   = (float*)(cursor + N_NODES);           // N
    float* disg  = dis + N_NODES;                        // N
    float* hw    = disg + N_NODES;                       // 32N
    int*   csr_s = (int*)(hw + (size_t)32 * N_NODES);    // E
    float* csr_wl = (float*)(csr_s + N_EDGES);           // E
    float* csr_wg = csr_wl + N_EDGES;                    // E

    hipMemsetAsync(cs, 0, (2 * (size_t)N_NODES + 4) * sizeof(int), stream);

    k_deg    <<<(N_EDGES + 255) / 256, 256, 0, stream>>>(src, dst, cs, cd);
    k_alloc  <<<(N_NODES + 255) / 256, 256, 0, stream>>>(cs, cd, gcur, start,
                                                         cursor, dis, disg);
    k_scatter<<<(N_EDGES + 255) / 256, 256, 0, stream>>>(src, dst, dis, disg,
                                                         cursor, csr_s, csr_wl, csr_wg);
    k_node   <<<N_NODES / 8, 256, 0, stream>>>(x, csr_s, csr_wl, start, cd,
                                               W_xz, b_xz, b_hz, W_xh, b_xh, b_hh,
                                               W_gcn, hw);
    k_out    <<<N_NODES / 8, 256, 0, stream>>>(hw, csr_s, csr_wg, start, cd, disg,
                                               b_gcn, W_lin, b_lin, out);
}

// Round 3
// 407.454 us; speedup vs baseline: 1.4697x; 1.1511x over previous
//
#include <hip/hip_runtime.h>

#define N_NODES 100000
#define N_EDGES 1600000

// ---------------------------------------------------------------------------
// K1: integer degree counts.  cs <- out-degree(src), cd <- in-degree(dst)
// ---------------------------------------------------------------------------
__global__ __launch_bounds__(256) void k_deg(const int* __restrict__ src,
                                             const int* __restrict__ dst,
                                             int* __restrict__ cs,
                                             int* __restrict__ cd) {
    int e = blockIdx.x * 256 + threadIdx.x;
    if (e < N_EDGES) {
        atomicAdd(&cs[src[e]], 1);
        atomicAdd(&cd[dst[e]], 1);
    }
}

// ---------------------------------------------------------------------------
// K2: per-node normalizers + CSR slot allocation.
// ---------------------------------------------------------------------------
__global__ __launch_bounds__(256) void k_alloc(const int* __restrict__ cs,
                                               const int* __restrict__ cd,
                                               int* __restrict__ gcur,
                                               int* __restrict__ start,
                                               int* __restrict__ cursor,
                                               float* __restrict__ dis,
                                               float* __restrict__ disg) {
    int i = blockIdx.x * 256 + threadIdx.x;
    if (i < N_NODES) {
        int c = cs[i], d = cd[i];
        dis[i]  = c > 0 ? rsqrtf((float)c) : 0.0f;
        disg[i] = rsqrtf((float)d + 1.0f);
        int st = atomicAdd(gcur, d);   // wave-aggregated by LLVM
        start[i]  = st;
        cursor[i] = st;
    }
}

// ---------------------------------------------------------------------------
// K3: scatter edges into dst-grouped CSR with precomputed weights.
// ---------------------------------------------------------------------------
__global__ __launch_bounds__(256) void k_scatter(const int* __restrict__ src,
                                                 const int* __restrict__ dst,
                                                 const float* __restrict__ dis,
                                                 const float* __restrict__ disg,
                                                 int* __restrict__ cursor,
                                                 int* __restrict__ csr_s,
                                                 float* __restrict__ csr_wl,
                                                 float* __restrict__ csr_wg) {
    int e = blockIdx.x * 256 + threadIdx.x;
    if (e < N_EDGES) {
        int s = src[e], d = dst[e];
        int pos = atomicAdd(&cursor[d], 1);
        csr_s[pos]  = s;
        csr_wl[pos] = -(dis[s] * dis[d]);
        csr_wg[pos] = disg[s] * disg[d];
    }
}

// ---------------------------------------------------------------------------
// K4: fused Lx-gather + GRU-gate GEMMs + GCN weight GEMM.
// Gather batched 8-wide: all index/weight loads issue, then 8 independent
// 128B row gathers in flight, then FMAs.  Tail via weight-zero clamping.
// ---------------------------------------------------------------------------
__global__ __launch_bounds__(256) void k_node(
        const float* __restrict__ x,
        const int* __restrict__ csr_s, const float* __restrict__ csr_wl,
        const int* __restrict__ start, const int* __restrict__ cd,
        const float* __restrict__ W_xz, const float* __restrict__ b_xz,
        const float* __restrict__ b_hz,
        const float* __restrict__ W_xh, const float* __restrict__ b_xh,
        const float* __restrict__ b_hh,
        const float* __restrict__ W_gcn,
        float* __restrict__ hw) {
    __shared__ float sW[5 * 1024];   // Wz0,Wz1,Wh0,Wh1,Wgcn  (k-major: [k][f])
    __shared__ float sbz[32], sbh[32];
    int tid = threadIdx.x;
    for (int i = tid; i < 2048; i += 256) { sW[i] = W_xz[i]; sW[2048 + i] = W_xh[i]; }
    for (int i = tid; i < 1024; i += 256) { sW[4096 + i] = W_gcn[i]; }
    if (tid < 32) { sbz[tid] = b_xz[tid] + b_hz[tid]; sbh[tid] = b_xh[tid] + b_hh[tid]; }
    __syncthreads();

    int node = blockIdx.x * 8 + (tid >> 5);   // N % 8 == 0, no tail
    int lane = tid & 31;
    int st = start[node], cn = cd[node];

    // --- batched register gather of Lx (8 row-loads in flight) ---
    float lv = 0.0f;
    for (int j = 0; j < cn; j += 8) {
        int s[8]; float w[8];
#pragma unroll
        for (int u = 0; u < 8; ++u) {
            int jj = j + u;
            int jc = jj < cn ? jj : cn - 1;        // clamp (cn >= 1 here)
            s[u] = csr_s[st + jc];
            float ww = csr_wl[st + jc];
            w[u] = jj < cn ? ww : 0.0f;
        }
        float v[8];
#pragma unroll
        for (int u = 0; u < 8; ++u) v[u] = x[s[u] * 32 + lane];
#pragma unroll
        for (int u = 0; u < 8; ++u) lv = fmaf(w[u], v[u], lv);
    }

    const float* Wz0 = sW;
    const float* Wz1 = sW + 1024;
    const float* Wh0 = sW + 2048;
    const float* Wh1 = sW + 3072;
    const float* Wg  = sW + 4096;

    float xv = x[node * 32 + lane];
    float z = sbz[lane], t = sbh[lane];
#pragma unroll
    for (int k = 0; k < 32; ++k) {
        float xk = __shfl(xv, k, 32);
        float lk = __shfl(lv, k, 32);
        z = fmaf(xk, Wz0[k * 32 + lane], z);
        z = fmaf(lk, Wz1[k * 32 + lane], z);
        t = fmaf(xk, Wh0[k * 32 + lane], t);
        t = fmaf(lk, Wh1[k * 32 + lane], t);
    }
    float Z = 1.0f / (1.0f + expf(-z));
    float H = (1.0f - Z) * tanhf(t);

    float hwv = 0.0f;
#pragma unroll
    for (int k = 0; k < 32; ++k) {
        float Hk = __shfl(H, k, 32);
        hwv = fmaf(Hk, Wg[k * 32 + lane], hwv);
    }
    hw[node * 32 + lane] = hwv;
}

// ---------------------------------------------------------------------------
// K5: fused GCN-gather + self-loop + bias + relu + W_lin dot (batched 8-wide).
// ---------------------------------------------------------------------------
__global__ __launch_bounds__(256) void k_out(
        const float* __restrict__ hw,
        const int* __restrict__ csr_s, const float* __restrict__ csr_wg,
        const int* __restrict__ start, const int* __restrict__ cd,
        const float* __restrict__ disg,
        const float* __restrict__ b_gcn,
        const float* __restrict__ W_lin, const float* __restrict__ b_lin,
        float* __restrict__ out) {
    int tid = threadIdx.x;
    int node = blockIdx.x * 8 + (tid >> 5);
    int lane = tid & 31;
    int st = start[node], cn = cd[node];

    float acc = 0.0f;
    for (int j = 0; j < cn; j += 8) {
        int s[8]; float w[8];
#pragma unroll
        for (int u = 0; u < 8; ++u) {
            int jj = j + u;
            int jc = jj < cn ? jj : cn - 1;
            s[u] = csr_s[st + jc];
            float ww = csr_wg[st + jc];
            w[u] = jj < cn ? ww : 0.0f;
        }
        float v[8];
#pragma unroll
        for (int u = 0; u < 8; ++u) v[u] = hw[s[u] * 32 + lane];
#pragma unroll
        for (int u = 0; u < 8; ++u) acc = fmaf(w[u], v[u], acc);
    }

    float dg = disg[node];
    acc = fmaf(dg * dg, hw[node * 32 + lane], acc);   // self loop

    float v = fmaxf(acc + b_gcn[lane], 0.0f) * W_lin[lane];
#pragma unroll
    for (int o = 16; o > 0; o >>= 1) v += __shfl_xor(v, o, 32);
    if (lane == 0) out[node] = v + b_lin[0];
}

extern "C" void kernel_launch(void* const* d_in, const int* in_sizes, int n_in,
                              void* d_out, int out_size, void* d_ws, size_t ws_size,
                              hipStream_t stream) {
    const float* x     = (const float*)d_in[0];
    const int*   ei    = (const int*)d_in[1];
    const int*   src   = ei;
    const int*   dst   = ei + N_EDGES;
    const float* W_xz  = (const float*)d_in[2];
    const float* b_xz  = (const float*)d_in[3];
    const float* b_hz  = (const float*)d_in[5];
    // W_xr/b_xr/W_hr/b_hr (d_in[6..9]) are dead: R only multiplies H0 == 0.
    const float* W_xh  = (const float*)d_in[10];
    const float* b_xh  = (const float*)d_in[11];
    const float* b_hh  = (const float*)d_in[13];
    const float* W_gcn = (const float*)d_in[14];
    const float* b_gcn = (const float*)d_in[15];
    const float* W_lin = (const float*)d_in[16];
    const float* b_lin = (const float*)d_in[17];
    float* out = (float*)d_out;

    // Workspace layout.  Zeroed region first: [cs N][cd N][gcur 4] ints.
    int* wsi     = (int*)d_ws;
    int* cs      = wsi;                                  // N
    int* cd      = cs + N_NODES;                         // N
    int* gcur    = cd + N_NODES;                         // 4 (1 used)
    int* start   = gcur + 4;                             // N
    int* cursor  = start + N_NODES;                      // N
    float* dis   = (float*)(cursor + N_NODES);           // N
    float* disg  = dis + N_NODES;                        // N
    float* hw    = disg + N_NODES;                       // 32N
    int*   csr_s = (int*)(hw + (size_t)32 * N_NODES);    // E
    float* csr_wl = (float*)(csr_s + N_EDGES);           // E
    float* csr_wg = csr_wl + N_EDGES;                    // E

    hipMemsetAsync(cs, 0, (2 * (size_t)N_NODES + 4) * sizeof(int), stream);

    k_deg    <<<(N_EDGES + 255) / 256, 256, 0, stream>>>(src, dst, cs, cd);
    k_alloc  <<<(N_NODES + 255) / 256, 256, 0, stream>>>(cs, cd, gcur, start,
                                                         cursor, dis, disg);
    k_scatter<<<(N_EDGES + 255) / 256, 256, 0, stream>>>(src, dst, dis, disg,
                                                         cursor, csr_s, csr_wl, csr_wg);
    k_node   <<<N_NODES / 8, 256, 0, stream>>>(x, csr_s, csr_wl, start, cd,
                                               W_xz, b_xz, b_hz, W_xh, b_xh, b_hh,
                                               W_gcn, hw);
    k_out    <<<N_NODES / 8, 256, 0, stream>>>(hw, csr_s, csr_wg, start, cd, disg,
                                               b_gcn, W_lin, b_lin, out);
}

// Round 4
// 385.603 us; speedup vs baseline: 1.5530x; 1.0567x over previous
//
#include <hip/hip_runtime.h>

#define N_NODES 100000
#define N_EDGES 1600000

// ---- bf16 helpers (RNE) ----------------------------------------------------
__device__ __forceinline__ float bflo(unsigned u) { return __uint_as_float(u << 16); }
__device__ __forceinline__ float bfhi(unsigned u) { return __uint_as_float(u & 0xffff0000u); }
__device__ __forceinline__ unsigned short f2bf(float f) {
    unsigned u = __float_as_uint(f);
    return (unsigned short)((u + 0x7fff + ((u >> 16) & 1)) >> 16);
}

// ---------------------------------------------------------------------------
// K0: convert x (f32) -> xb (bf16), 3.2M elements.
// ---------------------------------------------------------------------------
__global__ __launch_bounds__(256) void k_cvt(const float* __restrict__ x,
                                             unsigned short* __restrict__ xb) {
    int i = blockIdx.x * 256 + threadIdx.x;
    if (i < N_NODES * 32) xb[i] = f2bf(x[i]);
}

// ---------------------------------------------------------------------------
// K1: integer degree counts.  cs <- out-degree(src), cd <- in-degree(dst)
// ---------------------------------------------------------------------------
__global__ __launch_bounds__(256) void k_deg(const int* __restrict__ src,
                                             const int* __restrict__ dst,
                                             int* __restrict__ cs,
                                             int* __restrict__ cd) {
    int e = blockIdx.x * 256 + threadIdx.x;
    if (e < N_EDGES) {
        atomicAdd(&cs[src[e]], 1);
        atomicAdd(&cd[dst[e]], 1);
    }
}

// ---------------------------------------------------------------------------
// K2: per-node normalizers + CSR slot allocation.
// ---------------------------------------------------------------------------
__global__ __launch_bounds__(256) void k_alloc(const int* __restrict__ cs,
                                               const int* __restrict__ cd,
                                               int* __restrict__ gcur,
                                               int* __restrict__ start,
                                               int* __restrict__ cursor,
                                               float* __restrict__ dis,
                                               float* __restrict__ disg) {
    int i = blockIdx.x * 256 + threadIdx.x;
    if (i < N_NODES) {
        int c = cs[i], d = cd[i];
        dis[i]  = c > 0 ? rsqrtf((float)c) : 0.0f;
        disg[i] = rsqrtf((float)d + 1.0f);
        int st = atomicAdd(gcur, d);   // wave-aggregated by LLVM
        start[i]  = st;
        cursor[i] = st;
    }
}

// ---------------------------------------------------------------------------
// K3: scatter edges into dst-grouped CSR with precomputed weights.
// ---------------------------------------------------------------------------
__global__ __launch_bounds__(256) void k_scatter(const int* __restrict__ src,
                                                 const int* __restrict__ dst,
                                                 const float* __restrict__ dis,
                                                 const float* __restrict__ disg,
                                                 int* __restrict__ cursor,
                                                 int* __restrict__ csr_s,
                                                 float* __restrict__ csr_wl,
                                                 float* __restrict__ csr_wg) {
    int e = blockIdx.x * 256 + threadIdx.x;
    if (e < N_EDGES) {
        int s = src[e], d = dst[e];
        int pos = atomicAdd(&cursor[d], 1);
        csr_s[pos]  = s;
        csr_wl[pos] = -(dis[s] * dis[d]);
        csr_wg[pos] = disg[s] * disg[d];
    }
}

// ---------------------------------------------------------------------------
// K4: fused Lx-gather (bf16, 16 rows in flight) + GRU GEMMs + GCN weight GEMM.
// Lanes 0-15 process even edges, 16-31 odd edges; each lane loads one uint
// (2 bf16 features) per edge-pair.  Halves recombined via shfl_xor(16).
// ---------------------------------------------------------------------------
__global__ __launch_bounds__(256) void k_node(
        const float* __restrict__ x, const unsigned short* __restrict__ xbs,
        const int* __restrict__ csr_s, const float* __restrict__ csr_wl,
        const int* __restrict__ start, const int* __restrict__ cd,
        const float* __restrict__ W_xz, const float* __restrict__ b_xz,
        const float* __restrict__ b_hz,
        const float* __restrict__ W_xh, const float* __restrict__ b_xh,
        const float* __restrict__ b_hh,
        const float* __restrict__ W_gcn,
        unsigned short* __restrict__ hwb) {
    __shared__ float sW[5 * 1024];   // Wz0,Wz1,Wh0,Wh1,Wgcn  (k-major: [k][f])
    __shared__ float sbz[32], sbh[32];
    int tid = threadIdx.x;
    for (int i = tid; i < 2048; i += 256) { sW[i] = W_xz[i]; sW[2048 + i] = W_xh[i]; }
    for (int i = tid; i < 1024; i += 256) { sW[4096 + i] = W_gcn[i]; }
    if (tid < 32) { sbz[tid] = b_xz[tid] + b_hz[tid]; sbh[tid] = b_xh[tid] + b_hh[tid]; }
    __syncthreads();

    int node = blockIdx.x * 8 + (tid >> 5);   // N % 8 == 0, no tail
    int lane = tid & 31;
    int st = start[node], cn = cd[node];
    int half = lane >> 4;          // 0: even edges, 1: odd edges
    int c16  = lane & 15;          // uint column within 64B bf16 row
    const unsigned* xb = (const unsigned*)xbs;

    // --- batched bf16 gather: 8 uint loads/lane = 16 rows in flight ---
    float accx = 0.0f, accy = 0.0f;
    for (int j = 0; j < cn; j += 16) {
        int s[8]; float w[8];
#pragma unroll
        for (int u = 0; u < 8; ++u) {
            int jj = j + 2 * u + half;
            int jc = jj < cn ? jj : cn - 1;        // clamp (cn >= 1 here)
            s[u] = csr_s[st + jc];
            float ww = csr_wl[st + jc];
            w[u] = jj < cn ? ww : 0.0f;
        }
        unsigned v[8];
#pragma unroll
        for (int u = 0; u < 8; ++u) v[u] = xb[s[u] * 16 + c16];
#pragma unroll
        for (int u = 0; u < 8; ++u) {
            accx = fmaf(w[u], bflo(v[u]), accx);
            accy = fmaf(w[u], bfhi(v[u]), accy);
        }
    }
    accx += __shfl_xor(accx, 16, 32);   // lane c16 holds feature 2*c16
    accy += __shfl_xor(accy, 16, 32);   // lane c16 holds feature 2*c16+1

    const float* Wz0 = sW;
    const float* Wz1 = sW + 1024;
    const float* Wh0 = sW + 2048;
    const float* Wh1 = sW + 3072;
    const float* Wg  = sW + 4096;

    float xv = x[node * 32 + lane];     // self term stays f32
    float z = sbz[lane], t = sbh[lane];
#pragma unroll
    for (int m = 0; m < 16; ++m) {
        float x0 = __shfl(xv,   2 * m,     32);
        float x1 = __shfl(xv,   2 * m + 1, 32);
        float l0 = __shfl(accx, m, 32);
        float l1 = __shfl(accy, m, 32);
        z = fmaf(x0, Wz0[(2 * m) * 32 + lane], z);
        z = fmaf(l0, Wz1[(2 * m) * 32 + lane], z);
        t = fmaf(x0, Wh0[(2 * m) * 32 + lane], t);
        t = fmaf(l0, Wh1[(2 * m) * 32 + lane], t);
        z = fmaf(x1, Wz0[(2 * m + 1) * 32 + lane], z);
        z = fmaf(l1, Wz1[(2 * m + 1) * 32 + lane], z);
        t = fmaf(x1, Wh0[(2 * m + 1) * 32 + lane], t);
        t = fmaf(l1, Wh1[(2 * m + 1) * 32 + lane], t);
    }
    float Z = 1.0f / (1.0f + expf(-z));
    float H = (1.0f - Z) * tanhf(t);

    float hwv = 0.0f;
#pragma unroll
    for (int k = 0; k < 32; ++k) {
        float Hk = __shfl(H, k, 32);
        hwv = fmaf(Hk, Wg[k * 32 + lane], hwv);
    }
    hwb[node * 32 + lane] = f2bf(hwv);
}

// ---------------------------------------------------------------------------
// K5: fused GCN-gather (bf16) + self-loop + bias + relu + W_lin dot.
// ---------------------------------------------------------------------------
__global__ __launch_bounds__(256) void k_out(
        const unsigned short* __restrict__ hwbs,
        const int* __restrict__ csr_s, const float* __restrict__ csr_wg,
        const int* __restrict__ start, const int* __restrict__ cd,
        const float* __restrict__ disg,
        const float* __restrict__ b_gcn,
        const float* __restrict__ W_lin, const float* __restrict__ b_lin,
        float* __restrict__ out) {
    int tid = threadIdx.x;
    int node = blockIdx.x * 8 + (tid >> 5);
    int lane = tid & 31;
    int st = start[node], cn = cd[node];
    int half = lane >> 4;
    int c16  = lane & 15;
    const unsigned* hb = (const unsigned*)hwbs;

    float accx = 0.0f, accy = 0.0f;
    for (int j = 0; j < cn; j += 16) {
        int s[8]; float w[8];
#pragma unroll
        for (int u = 0; u < 8; ++u) {
            int jj = j + 2 * u + half;
            int jc = jj < cn ? jj : cn - 1;
            s[u] = csr_s[st + jc];
            float ww = csr_wg[st + jc];
            w[u] = jj < cn ? ww : 0.0f;
        }
        unsigned v[8];
#pragma unroll
        for (int u = 0; u < 8; ++u) v[u] = hb[s[u] * 16 + c16];
#pragma unroll
        for (int u = 0; u < 8; ++u) {
            accx = fmaf(w[u], bflo(v[u]), accx);
            accy = fmaf(w[u], bfhi(v[u]), accy);
        }
    }
    accx += __shfl_xor(accx, 16, 32);
    accy += __shfl_xor(accy, 16, 32);

    // redistribute paired layout -> lane = feature
    float ax = __shfl(accx, lane >> 1, 32);
    float ay = __shfl(accy, lane >> 1, 32);
    float acc = (lane & 1) ? ay : ax;

    float dg = disg[node];
    float hws = bflo((unsigned)hwbs[node * 32 + lane]) ;  // self row, lane=feature
    acc = fmaf(dg * dg, hws, acc);

    float v = fmaxf(acc + b_gcn[lane], 0.0f) * W_lin[lane];
#pragma unroll
    for (int o = 16; o > 0; o >>= 1) v += __shfl_xor(v, o, 32);
    if (lane == 0) out[node] = v + b_lin[0];
}

extern "C" void kernel_launch(void* const* d_in, const int* in_sizes, int n_in,
                              void* d_out, int out_size, void* d_ws, size_t ws_size,
                              hipStream_t stream) {
    const float* x     = (const float*)d_in[0];
    const int*   ei    = (const int*)d_in[1];
    const int*   src   = ei;
    const int*   dst   = ei + N_EDGES;
    const float* W_xz  = (const float*)d_in[2];
    const float* b_xz  = (const float*)d_in[3];
    const float* b_hz  = (const float*)d_in[5];
    // W_xr/b_xr/W_hr/b_hr (d_in[6..9]) are dead: R only multiplies H0 == 0.
    const float* W_xh  = (const float*)d_in[10];
    const float* b_xh  = (const float*)d_in[11];
    const float* b_hh  = (const float*)d_in[13];
    const float* W_gcn = (const float*)d_in[14];
    const float* b_gcn = (const float*)d_in[15];
    const float* W_lin = (const float*)d_in[16];
    const float* b_lin = (const float*)d_in[17];
    float* out = (float*)d_out;

    // Workspace layout (ints unless noted).  Zeroed region first: [cs][cd][gcur].
    int* wsi     = (int*)d_ws;
    int* cs      = wsi;                                   // N
    int* cd      = cs + N_NODES;                          // N
    int* gcur    = cd + N_NODES;                          // 4 (1 used)
    int* start   = gcur + 4;                              // N
    int* cursor  = start + N_NODES;                       // N
    float* dis   = (float*)(cursor + N_NODES);            // N
    float* disg  = dis + N_NODES;                         // N
    unsigned short* xb  = (unsigned short*)(disg + N_NODES);     // 32N ushort
    unsigned short* hwb = xb + (size_t)32 * N_NODES;             // 32N ushort
    int*   csr_s = (int*)(hwb + (size_t)32 * N_NODES);    // E
    float* csr_wl = (float*)(csr_s + N_EDGES);            // E
    float* csr_wg = csr_wl + N_EDGES;                     // E

    hipMemsetAsync(cs, 0, (2 * (size_t)N_NODES + 4) * sizeof(int), stream);

    k_cvt    <<<(N_NODES * 32 + 255) / 256, 256, 0, stream>>>(x, xb);
    k_deg    <<<(N_EDGES + 255) / 256, 256, 0, stream>>>(src, dst, cs, cd);
    k_alloc  <<<(N_NODES + 255) / 256, 256, 0, stream>>>(cs, cd, gcur, start,
                                                         cursor, dis, disg);
    k_scatter<<<(N_EDGES + 255) / 256, 256, 0, stream>>>(src, dst, dis, disg,
                                                         cursor, csr_s, csr_wl, csr_wg);
    k_node   <<<N_NODES / 8, 256, 0, stream>>>(x, xb, csr_s, csr_wl, start, cd,
                                               W_xz, b_xz, b_hz, W_xh, b_xh, b_hh,
                                               W_gcn, hwb);
    k_out    <<<N_NODES / 8, 256, 0, stream>>>(hwb, csr_s, csr_wg, start, cd, disg,
                                               b_gcn, W_lin, b_lin, out);
}